// Round 11
// baseline (1458.378 us; speedup 1.0000x reference)
//
#include <hip/hip_runtime.h>
#include <stdint.h>

// Problem constants (fixed by the reference)
#define BROWS 8192
#define DIN   768
#define DLAT  12288
#define KTOP  64

#define LO_SCALE 4096.0f      // 2^12: keeps fp16 lo-terms normal
#define LO_INV   (1.0f / 4096.0f)

// np-association model ledger: Model 1 — single sequential fmaf chain over
// all k in [0,768), bias last.
//
// R0: k_enc_gemm -> 8-phase 256x128 pipelined schedule (total 2198 -> 1828).
// R1: k_topk -> 4-round radix-256 select + float4 I/O (total 1828 -> 1521).
// R2/R5: barrier restructuring: 502->467. Model: per-tile wall =
//     MFMA(1862 cyc/SIMD) + LDS(1536 cyc/CU) ADDITIVE — both waves/SIMD are
//     same-block siblings in barrier lockstep.
// R6/R7: cross-tile register prefetch dead (acc 128 VGPR leaves no room).
// R8: topk round-0 atomic-free byte probe (-36us, kept). GEMM = R5 (465us).
// R9: cross-block overlap (128x128, 64KB LDS, 2 blocks/CU) died to
//     "container failed twice". Full audit found NO deadlock mechanism
//     (staging map, vmcnt ledger, dbuf hazards, barrier uniformity, bounds,
//     VGPR budget all check). Infra base rate ~3/11 this session.
// R10 (this round): resubmit the SAME experiment as a variant (R4 lesson:
//     no byte-identical resubmits): merged waitcnt, pointer-swap rotation
//     (R5 idiom), R5-style prologue. Same reads, same per-element MFMA
//     order -> bitwise-identical H. Pre-commit: second container death =>
//     abandon 2-block family, revert to R8.

typedef _Float16 half8 __attribute__((ext_vector_type(8)));  // 8 x fp16 (4 VGPRs)
typedef __attribute__((ext_vector_type(4))) float float4v;   // 4 x fp32 acc

typedef __attribute__((address_space(3))) void lds_void_t;
typedef __attribute__((address_space(1))) void glob_void_t;

__device__ __forceinline__ unsigned short f2h_bits(float f) {
  _Float16 h = (_Float16)f;          // RNE
  return __builtin_bit_cast(unsigned short, h);
}
__device__ __forceinline__ float h_bits_to_f(unsigned short b) {
  return (float)__builtin_bit_cast(_Float16, b);
}

// ---- x [8192,768] fp32 -> (Xh, Xl) fp16 split; lo scaled by 2^12 ----------
__global__ __launch_bounds__(256) void k_cvt_split(const float* __restrict__ in,
                                                   unsigned short* __restrict__ hi,
                                                   unsigned short* __restrict__ lo,
                                                   int n4) {
  int i = blockIdx.x * 256 + threadIdx.x;
  if (i >= n4) return;
  float4 v = ((const float4*)in)[i];
  ushort4 h, l;
  h.x = f2h_bits(v.x); l.x = f2h_bits((v.x - h_bits_to_f(h.x)) * LO_SCALE);
  h.y = f2h_bits(v.y); l.y = f2h_bits((v.y - h_bits_to_f(h.y)) * LO_SCALE);
  h.z = f2h_bits(v.z); l.z = f2h_bits((v.z - h_bits_to_f(h.z)) * LO_SCALE);
  h.w = f2h_bits(v.w); l.w = f2h_bits((v.w - h_bits_to_f(h.w)) * LO_SCALE);
  ((ushort4*)hi)[i] = h;
  ((ushort4*)lo)[i] = l;
}

// ---- W_enc [768,12288] fp32 -> Wt_hi/Wt_lo [12288,768] fp16 (transpose+split)
__global__ __launch_bounds__(256) void k_transpose_split(const float* __restrict__ W,
                                                         unsigned short* __restrict__ Wth,
                                                         unsigned short* __restrict__ Wtl) {
  __shared__ float s[32][33];
  const int n0 = blockIdx.x * 32;
  const int k0 = blockIdx.y * 32;
  const int tx = threadIdx.x, ty = threadIdx.y;  // 32 x 8
#pragma unroll
  for (int i = 0; i < 4; i++)
    s[ty + 8 * i][tx] = W[(size_t)(k0 + ty + 8 * i) * DLAT + n0 + tx];
  __syncthreads();
#pragma unroll
  for (int i = 0; i < 4; i++) {
    int nl = ty + 8 * i;
    float v = s[tx][nl];
    unsigned short h = f2h_bits(v);
    unsigned short l = f2h_bits((v - h_bits_to_f(h)) * LO_SCALE);
    size_t o = (size_t)(n0 + nl) * DIN + k0 + tx;
    Wth[o] = h;
    Wtl[o] = l;
  }
}

// ---- encoder GEMM: H = X * Wt^T + b_enc, fp16 2-term split ------------------
// R10: 128x128 tile, 256 threads (4 waves: 2M x 2N, 64x64 per wave), BK=32.
// Double-buffer 2x32KB LDS -> 2 blocks/CU for cross-block pipe overlap.
// XOR bank swizzle (both-sides), setprio, ONE barrier per K-tile.
#define GBM 128
#define GBN 128
#define GBK 32

#define MFMA12(MI, AH, AL)                                                                   \
  do {                                                                                       \
    _Pragma("unroll") for (int ni = 0; ni < 4; ni++) {                                       \
      acc1[MI][ni] = __builtin_amdgcn_mfma_f32_16x16x32_f16(AH, bh[ni], acc1[MI][ni], 0, 0, 0); \
      acc2[MI][ni] = __builtin_amdgcn_mfma_f32_16x16x32_f16(AL, bh[ni], acc2[MI][ni], 0, 0, 0); \
      acc2[MI][ni] = __builtin_amdgcn_mfma_f32_16x16x32_f16(AH, bl[ni], acc2[MI][ni], 0, 0, 0); \
    }                                                                                        \
  } while (0)

#define STAGE1(R)                                                                            \
  __builtin_amdgcn_global_load_lds((glob_void_t*)(src[R] + kk2),                             \
                                   (lds_void_t*)(sb + loff[R]), 16, 0, 0)

__global__ __launch_bounds__(256, 2) void k_enc_gemm(const unsigned short* __restrict__ Xh,
                                                     const unsigned short* __restrict__ Xl,
                                                     const unsigned short* __restrict__ Wth,
                                                     const unsigned short* __restrict__ Wtl,
                                                     const float* __restrict__ b_enc,
                                                     float* __restrict__ H) {
  __shared__ unsigned short lds[2][16384];  // 2 x 32 KB = 64 KB -> 2 blocks/CU

  const int tid  = threadIdx.x;
  const int lane = tid & 63;
  const int wave = tid >> 6;          // 0..3
  const int wm   = wave >> 1;         // 0..1 (M half)
  const int wn   = wave & 1;          // 0..1 (N half)

  // Bijective XCD-aware swizzle: 6144 wgs, 6144/8 = 768 per XCD.
  const int wg = (blockIdx.x & 7) * 768 + (blockIdx.x >> 3);
  const int tm = wg / 96;             // 64 m-tiles
  const int tn = wg - tm * 96;        // 96 n-tiles (consecutive wgs share A-panel)
  const int m_blk = tm * GBM;
  const int n_blk = tn * GBN;

  // ---- staging setup: chunk c = wave*8+r = 1 KB = 16 rows of one stream ----
  // Streams: c in [0,8)=A-hi, [8,16)=A-lo, [16,24)=B-hi, [24,32)=B-lo.
  // LDS dest linear; bank swizzle via pre-swizzled GLOBAL source quarter:
  // physical quarter (lane&3) holds logical quarter (lane&3)^((row>>1)&3).
  const int qlog = (lane & 3) ^ ((lane >> 3) & 3);
  const unsigned short* src[8];
  int loff[8];
#pragma unroll
  for (int r = 0; r < 8; r++) {
    const int c = wave * 8 + r;          // 0..31
    const int k16 = (c & 7) * 16;
    const unsigned short* base;
    int grow;
    if (c < 8)       { base = Xh;  grow = m_blk + k16; }
    else if (c < 16) { base = Xl;  grow = m_blk + k16; }
    else if (c < 24) { base = Wth; grow = n_blk + k16; }
    else             { base = Wtl; grow = n_blk + k16; }
    src[r]  = base + (size_t)(grow + (lane >> 2)) * DIN + qlog * 8;
    loff[r] = c * 512;
  }

  // ---- fragment-read offsets (ushort units), same XOR on the read side ----
  // LDS map: A-hi [0,4096) A-lo [4096,8192) B-hi [8192,12288) B-lo [12288,16384)
  const int qp   = (lane >> 4) ^ ((lane >> 1) & 3);
  const int aoff = (wm * 64 + (lane & 15)) * 32 + qp * 8;         // A-hi; +4096 for lo
  const int boff = 8192 + (wn * 64 + (lane & 15)) * 32 + qp * 8;  // B-hi; +4096 for lo

  float4v acc1[4][4];  // hi*hi
  float4v acc2[4][4];  // hi*lo + lo*hi (carries 2^12)
#pragma unroll
  for (int i = 0; i < 4; i++)
#pragma unroll
    for (int j = 0; j < 4; j++) { acc1[i][j] = (float4v)0.0f; acc2[i][j] = (float4v)0.0f; }

  // ---- prologue: stage K-tile 0 into buf 0 (8 loads per thread) ----
#pragma unroll
  for (int r = 0; r < 8; r++)
    __builtin_amdgcn_global_load_lds((glob_void_t*)(src[r]),
                                     (lds_void_t*)(&lds[0][loff[r]]), 16, 0, 0);
  asm volatile("s_waitcnt vmcnt(0)" ::: "memory");
  asm volatile("s_barrier" ::: "memory");   // tile 0 fully landed (all waves)

  const unsigned short* p_cur = lds[0];
  unsigned short*       p_stg = lds[1];

#pragma unroll 1
  for (int t = 0; t < 24; t++) {
    const unsigned short* lb = p_cur;
    unsigned short*       sb = p_stg;
    const int kk2 = t * GBK + GBK;          // stage tile t+1
    const bool do_stage = (t < 23);

    half8 bh[4], bl[4], ah0, al0, ah1, al1;

    // -------- half 1: B-frags + A mi0/mi1 || stage 4 -> 24 MFMA (no barrier)
#pragma unroll
    for (int ni = 0; ni < 4; ni++) {
      bh[ni] = *(const half8*)(lb + boff + ni * 512);
      bl[ni] = *(const half8*)(lb + boff + 4096 + ni * 512);
    }
    ah0 = *(const half8*)(lb + aoff);
    al0 = *(const half8*)(lb + aoff + 4096);
    ah1 = *(const half8*)(lb + aoff + 512);
    al1 = *(const half8*)(lb + aoff + 4096 + 512);
    if (do_stage) { STAGE1(0); STAGE1(1); STAGE1(2); STAGE1(3); }
    __builtin_amdgcn_s_setprio(1);
    MFMA12(0, ah0, al0);
    MFMA12(1, ah1, al1);
    __builtin_amdgcn_s_setprio(0);

    // -------- half 2: A mi2/mi3 || stage 4 -> 24 MFMA (no barrier) ----------
    ah0 = *(const half8*)(lb + aoff + 1024);
    al0 = *(const half8*)(lb + aoff + 4096 + 1024);
    ah1 = *(const half8*)(lb + aoff + 1536);
    al1 = *(const half8*)(lb + aoff + 4096 + 1536);
    if (do_stage) { STAGE1(4); STAGE1(5); STAGE1(6); STAGE1(7); }
    __builtin_amdgcn_s_setprio(1);
    MFMA12(2, ah0, al0);
    MFMA12(3, ah1, al1);
    __builtin_amdgcn_s_setprio(0);

    // -------- tile boundary: the ONLY barrier per tile ----------------------
    // (vmcnt(0) drain is hidden by the co-resident sibling block)
    asm volatile("s_waitcnt vmcnt(0) lgkmcnt(0)" ::: "memory");
    asm volatile("s_barrier" ::: "memory");

    // swap buffers (R5 pointer-swap idiom)
    unsigned short* tmp = (unsigned short*)p_cur;
    p_cur = p_stg;
    p_stg = tmp;
  }

  // ---- epilogue: identical combine (wm,wn now in {0,1}) ----
  const int col   = lane & 15;
  const int rbase = (lane >> 4) * 4;
#pragma unroll
  for (int ni = 0; ni < 4; ni++) {
    const int n = n_blk + wn * 64 + ni * 16 + col;
    const float bias = b_enc[n];
#pragma unroll
    for (int mi = 0; mi < 4; mi++) {
#pragma unroll
      for (int r = 0; r < 4; r++) {
        const int m = m_blk + wm * 64 + mi * 16 + rbase + r;
        H[(size_t)m * DLAT + n] = acc1[mi][ni][r] + acc2[mi][ni][r] * LO_INV + bias;
      }
    }
  }
}

// ---- top-64 per row with np-simulated boundary arbitration -----------------
// R1: radix-256 select. R8: round 0 = atomic-free descending byte probe
// (bit-identical s_cur/s_krem); rounds 1-3 keep the histogram.
#define UMARGIN 4e-4f
#define UCAP 64
__device__ __forceinline__ float key_to_f32(unsigned k) {
  unsigned u = (k & 0x80000000u) ? (k & 0x7fffffffu) : ~k;
  return __uint_as_float(u);
}
// keys[j] (j = 4*j4+c) holds element idx = 4*tid + 1024*j4 + c of the row.
#define KIDX(J) (4 * tid + 1024 * ((J) >> 2) + ((J) & 3))

__global__ __launch_bounds__(256) void k_topk(float* __restrict__ Z,
                                              const float* __restrict__ x,
                                              const float* __restrict__ We,
                                              const float* __restrict__ b_enc,
                                              int* __restrict__ idxl,
                                              float* __restrict__ vall) {
  const int row = blockIdx.x;
  const int tid = threadIdx.x;
  const int lane = tid & 63, wid = tid >> 6;
  float* zr = Z + (size_t)row * DLAT;

  // -- load row as float4, monotone-map to sortable unsigned keys --
  unsigned keys[48];
#pragma unroll
  for (int j4 = 0; j4 < 12; j4++) {
    const float4 v4 = ((const float4*)zr)[tid + 256 * j4];
    const float vv[4] = {v4.x, v4.y, v4.z, v4.w};
#pragma unroll
    for (int c = 0; c < 4; c++) {
      const unsigned u = __float_as_uint(vv[c]);
      keys[4 * j4 + c] = (u & 0x80000000u) ? ~u : (u | 0x80000000u);
    }
  }

  __shared__ int hist[1024];          // 4 wave-private 256-bin histograms (rounds 1-3)
  __shared__ unsigned wmax[4];
  __shared__ unsigned s_kmax;
  __shared__ unsigned s_cur;
  __shared__ int wsum[4];
  __shared__ int s_total;
  __shared__ int s_krem;
  __shared__ int s_nu, s_ncert, s_out;
  __shared__ int   u_idx[UCAP];
  __shared__ float u_vf[UCAP];
  __shared__ unsigned char u_sel[UCAP];

  // ===== round 0 replacement: descending byte probe (no atomics) =====
  // (a) row max key
  unsigned kmax = 0;
#pragma unroll
  for (int j = 0; j < 48; j++) kmax = max(kmax, keys[j]);
#pragma unroll
  for (int off = 32; off > 0; off >>= 1) {
    const unsigned tmp = (unsigned)__shfl_xor((int)kmax, off);
    kmax = max(kmax, tmp);
  }
  if (lane == 0) wmax[wid] = kmax;
  __syncthreads();
  if (tid == 0)
    s_kmax = max(max(wmax[0], wmax[1]), max(wmax[2], wmax[3]));
  __syncthreads();

  // (b) probe bytes B, B-1, B-2, ... two at a time (packed counts).
  // Invariant: cum = #keys with top byte > b (uniform across threads).
  int b = (int)(s_kmax >> 24);
  int cum = 0;
  int bsel = 0, krem0 = KTOP;
#pragma unroll 1
  for (;;) {
    int c = 0;
#pragma unroll
    for (int j = 0; j < 48; j++) {
      const int by = (int)(keys[j] >> 24);
      c += (by == b) ? 0x10000 : 0;
      c += (by == b - 1) ? 1 : 0;
    }
#pragma unroll
    for (int off = 32; off > 0; off >>= 1) c += __shfl_down(c, off);
    if (lane == 0) wsum[wid] = c;
    __syncthreads();
    if (tid == 0) s_total = wsum[0] + wsum[1] + wsum[2] + wsum[3];
    __syncthreads();
    const int chi = s_total >> 16;          // count(byte == b)
    const int clo = s_total & 0xffff;       // count(byte == b-1)
    if (cum + chi >= KTOP) { bsel = b;     krem0 = KTOP - cum;        break; }
    if (cum + chi + clo >= KTOP) { bsel = b - 1; krem0 = KTOP - cum - chi; break; }
    cum += chi + clo;
    b -= 2;
    if (b < 0) { bsel = 0; krem0 = KTOP - cum; break; }  // unreachable safety
  }
  if (tid == 0) { s_cur = (unsigned)bsel << 24; s_krem = krem0; }
  __syncthreads();

  // ===== rounds 1-3: radix-256 histogram refinement (few participants) =====
#pragma unroll
  for (int r = 1; r < 4; r++) {
    const int sh = 24 - 8 * r;
    const unsigned pre = s_cur;       // stable since trailing barrier
    hist[tid] = 0; hist[tid + 256] = 0; hist[tid + 512] = 0; hist[tid + 768] = 0;
    __syncthreads();
#pragma unroll
    for (int j = 0; j < 48; j++) {
      const unsigned k = keys[j];
      // participation: high bits match settled prefix
      if ((((unsigned long long)(k ^ pre)) >> (sh + 8)) == 0ull)
        atomicAdd(&hist[wid * 256 + ((k >> sh) & 255)], 1);
    }
    __syncthreads();
    if (wid == 0) {
      // lane l owns bins 4l..4l+3; reduce the 4 wave copies
      const int b0 = 4 * lane;
      int t0 = hist[b0]     + hist[256 + b0]     + hist[512 + b0]     + hist[768 + b0];
      int t1 = hist[b0 + 1] + hist[256 + b0 + 1] + hist[512 + b0 + 1] + hist[768 + b0 + 1];
      int t2 = hist[b0 + 2] + hist[256 + b0 + 2] + hist[512 + b0 + 2] + hist[768 + b0 + 2];
      int t3 = hist[b0 + 3] + hist[256 + b0 + 3] + hist[512 + b0 + 3] + hist[768 + b0 + 3];
      const int s3 = t3, s2 = t2 + s3, s1 = t1 + s2, s0 = t0 + s1;
      // inclusive suffix-sum of s0 across lanes (guarded shfl_down)
      int hi = s0;
#pragma unroll
      for (int off = 1; off < 64; off <<= 1) {
        const int tmp = __shfl_down(hi, off);
        if (lane + off < 64) hi += tmp;
      }
      // S(bin) = count of participating keys with bin >= b
      const int krem = s_krem;
      const int S0 = hi, S1 = hi - s0 + s1, S2 = hi - s0 + s2, S3 = hi - s0 + s3;
      int bb = -1;
      if (S0 >= krem) bb = b0;
      if (S1 >= krem) bb = b0 + 1;
      if (S2 >= krem) bb = b0 + 2;
      if (S3 >= krem) bb = b0 + 3;
#pragma unroll
      for (int off = 1; off < 64; off <<= 1) bb = max(bb, __shfl_xor(bb, off));
      if ((bb >> 2) == lane) {
        const int c = bb & 3;
        const int Sb = (c == 0) ? S0 : (c == 1) ? S1 : (c == 2) ? S2 : S3;
        const int tc = (c == 0) ? t0 : (c == 1) ? t1 : (c == 2) ? t2 : t3;
        s_krem = krem - (Sb - tc);    // keys strictly above bin bb are settled-in
        s_cur  = pre | ((unsigned)bb << sh);
      }
    }
    __syncthreads();
  }
  const unsigned cur = s_cur;         // == 64th-largest key bit pattern
  const float h64 = key_to_f32(cur);

  if (tid == 0) { s_nu = 0; s_ncert = 0; s_out = 0; }
  __syncthreads();

  // -- classify: certain (v > h64+m) / uncertain (|v-h64| <= m) / out --
  signed char uslot[48];
  int certc = 0;
#pragma unroll
  for (int j = 0; j < 48; j++) {
    const float v = key_to_f32(keys[j]);
    uslot[j] = -1;
    if (v > h64 + UMARGIN) {
      certc++;
    } else if (v >= h64 - UMARGIN) {
      int pos = atomicAdd(&s_nu, 1);
      if (pos < UCAP) {
        u_idx[pos] = KIDX(j);
        u_vf[pos]  = v;
        uslot[j] = (signed char)pos;
      }
    }
  }
  if (certc) atomicAdd(&s_ncert, certc);
  __syncthreads();

  const int nu = min(s_nu, UCAP);
  int t = KTOP - s_ncert;                 // open slots for uncertain set
  t = max(0, min(t, nu));

  if (nu > t) {
    // genuine contest: Model 1 — single sequential fp32 fmaf chain over all
    // of k (no blocking), bias added last.
    if (tid < nu) {
      const int ci = u_idx[tid];
      const float* xr = x + (size_t)row * DIN;
      float c = 0.0f;
      for (int k = 0; k < DIN; k++)
        c = fmaf(xr[k], We[(size_t)k * DLAT + ci], c);
      u_vf[tid] = c + b_enc[ci];
    }
    __syncthreads();
    // rank on sim values (no bitwise ties occur — r7 == r4 proved it)
    if (tid == 0) {
      for (int u = 0; u < nu; u++) {
        int rank = 0;
        for (int v2 = 0; v2 < nu; v2++)
          rank += (u_vf[v2] > u_vf[u]) ||
                  (u_vf[v2] == u_vf[u] && u_idx[v2] > u_idx[u]);
        u_sel[u] = (rank < t) ? 1 : 0;
      }
    }
  } else {
    // all uncertain elements are selected; approx values stand
    if (tid < nu) u_sel[tid] = 1;
  }
  __syncthreads();

  // -- final write: z row in place (float4) + compact (idx, val) lists --
#pragma unroll
  for (int j4 = 0; j4 < 12; j4++) {
    float oc[4];
#pragma unroll
    for (int c = 0; c < 4; c++) {
      const int j = 4 * j4 + c;
      const int idx = 4 * tid + 1024 * j4 + c;
      const float v = key_to_f32(keys[j]);
      bool sel = false;
      float outv = 0.0f;
      if (v > h64 + UMARGIN) {
        sel = true; outv = v;
      } else if (uslot[j] >= 0 && u_sel[(int)uslot[j]]) {
        sel = true; outv = u_vf[(int)uslot[j]];
      }
      oc[c] = sel ? outv : 0.0f;
      if (sel) {
        int s = atomicAdd(&s_out, 1);
        if (s < KTOP) {
          idxl[row * KTOP + s] = idx;
          vall[row * KTOP + s] = outv;
        }
      }
    }
    float4 o;
    o.x = oc[0]; o.y = oc[1]; o.z = oc[2]; o.w = oc[3];
    ((float4*)zr)[tid + 256 * j4] = o;
  }
}

// ---- sparse decoder: recon = z @ W_dec + b_dec (fp32) ----------------------
__global__ __launch_bounds__(192) void k_dec(const int* __restrict__ idxl,
                                             const float* __restrict__ vall,
                                             const float* __restrict__ Wd,
                                             const float* __restrict__ b_dec,
                                             float* __restrict__ R) {
  const int row = blockIdx.x;
  const int t = threadIdx.x;
  __shared__ int   sidx[KTOP];
  __shared__ float sval[KTOP];
  if (t < KTOP) {
    sidx[t] = idxl[row * KTOP + t];
    sval[t] = vall[row * KTOP + t];
  }
  __syncthreads();
  const int c = t * 4;
  float4 acc = *(const float4*)(b_dec + c);
#pragma unroll 4
  for (int j = 0; j < KTOP; j++) {
    float4 w = *(const float4*)(Wd + (size_t)sidx[j] * DIN + c);
    const float v = sval[j];
    acc.x += v * w.x;
    acc.y += v * w.y;
    acc.z += v * w.z;
    acc.w += v * w.w;
  }
  *(float4*)(R + (size_t)row * DIN + c) = acc;
}

// ----------------------------------------------------------------------------
extern "C" void kernel_launch(void* const* d_in, const int* in_sizes, int n_in,
                              void* d_out, int out_size, void* d_ws, size_t ws_size,
                              hipStream_t stream) {
  const float* x     = (const float*)d_in[0];
  const float* W_enc = (const float*)d_in[1];
  const float* b_enc = (const float*)d_in[2];
  const float* W_dec = (const float*)d_in[3];
  const float* b_dec = (const float*)d_in[4];

  float* recon = (float*)d_out;                       // [8192, 768]
  float* z     = (float*)d_out + (size_t)BROWS * DIN; // [8192, 12288] (doubles as h)

  // X fp16 split lives in the recon region (exact 25,165,824 B fit); consumed
  // by the GEMM, then overwritten by the decoder.
  unsigned short* Xh = (unsigned short*)recon;
  unsigned short* Xl = Xh + (size_t)BROWS * DIN;

  char* ws = (char*)d_ws;
  unsigned short* Wth = (unsigned short*)ws;                  // 18,874,368 B
  unsigned short* Wtl = (unsigned short*)(ws + 18874368);     // 18,874,368 B
  int*   idxl = (int*)(ws + 2 * 18874368);                    //  2,097,152 B
  float* vall = (float*)(ws + 2 * 18874368 + 2097152);        //  2,097,152 B

  k_cvt_split<<<6144, 256, 0, stream>>>(x, Xh, Xl, (BROWS * DIN) / 4);
  k_transpose_split<<<dim3(DLAT / 32, DIN / 32), dim3(32, 8), 0, stream>>>(W_enc, Wth, Wtl);
  k_enc_gemm<<<dim3(6144), dim3(256), 0, stream>>>(Xh, Xl, Wth, Wtl, b_enc, z);
  k_topk<<<BROWS, 256, 0, stream>>>(z, x, W_enc, b_enc, idxl, vall);
  k_dec<<<BROWS, 192, 0, stream>>>(idxl, vall, W_dec, b_dec, recon);
}